// Round 7
// baseline (151.230 us; speedup 1.0000x reference)
//
#include <hip/hip_runtime.h>
#include <hip/hip_bf16.h>

#define NN 4096
#define NFEAT 256
#define NHID1 64
#define NHID2 32
#define NCLASS 8
#define NHEADS 4
#define NADJ 2
#define CAP 128

// ---------------------------------------------------------------------------
// Register-blocked tiled GEMM body (used by k1): C = A @ B, fused GAT
// attention coefficients: fsrc[row] = Crow.a[0,:], fdst = Crow.a[1,:].
template <int KDIM, int NDIM, int RPTY>
__device__ __forceinline__ void gemm_body(
    const float* __restrict__ A, const float* __restrict__ B,
    float* __restrict__ C, const float* __restrict__ ag,
    float* __restrict__ fsrc, float* __restrict__ fdst, const int row0b,
    float* __restrict__ sA, float* __restrict__ sB) {
  constexpr int KT = 32;
  constexpr int TX = NDIM / 4;
  constexpr int TY = 256 / TX;
  constexpr int BR = TY * RPTY;
  constexpr int LDA = BR + 4;
  constexpr int LDB = NDIM + 4;
  const int tid = threadIdx.x;
  const int tx = tid % TX, ty = tid / TX;
  const int c0 = tx * 4;
  float acc[RPTY][4];
#pragma unroll
  for (int i = 0; i < RPTY; ++i)
#pragma unroll
    for (int j = 0; j < 4; ++j) acc[i][j] = 0.f;

  for (int kt = 0; kt < KDIM; kt += KT) {
    __syncthreads();
    for (int i = tid; i < BR * (KT / 4); i += 256) {
      const int r = i / (KT / 4), e = i % (KT / 4);
      const float4 v = *(const float4*)(A + (size_t)(row0b + r) * KDIM + kt + e * 4);
      sA[(e * 4 + 0) * LDA + r] = v.x;
      sA[(e * 4 + 1) * LDA + r] = v.y;
      sA[(e * 4 + 2) * LDA + r] = v.z;
      sA[(e * 4 + 3) * LDA + r] = v.w;
    }
    for (int i = tid; i < KT * (NDIM / 4); i += 256) {
      const int k = i / (NDIM / 4), cc = i % (NDIM / 4);
      *(float4*)&sB[k * LDB + cc * 4] = *(const float4*)(B + (size_t)(kt + k) * NDIM + cc * 4);
    }
    __syncthreads();
#pragma unroll
    for (int k = 0; k < KT; ++k) {
      const float4 t = *(const float4*)&sA[k * LDA + ty * 4];
      const float a4[4] = {t.x, t.y, t.z, t.w};
      const float4 bv = *(const float4*)&sB[k * LDB + c0];
      const float b4[4] = {bv.x, bv.y, bv.z, bv.w};
#pragma unroll
      for (int i = 0; i < RPTY; ++i)
#pragma unroll
        for (int j = 0; j < 4; ++j) acc[i][j] += a4[i] * b4[j];
    }
  }
#pragma unroll
  for (int i = 0; i < RPTY; ++i) {
    const int row = row0b + ty * RPTY + i;
    float4 o;
    o.x = acc[i][0]; o.y = acc[i][1]; o.z = acc[i][2]; o.w = acc[i][3];
    *(float4*)&C[(size_t)row * NDIM + c0] = o;
  }
  float aS[4], aD[4];
#pragma unroll
  for (int j = 0; j < 4; ++j) { aS[j] = ag[c0 + j]; aD[j] = ag[NDIM + c0 + j]; }
#pragma unroll
  for (int i = 0; i < RPTY; ++i) {
    float s = 0.f, d = 0.f;
#pragma unroll
    for (int j = 0; j < 4; ++j) { s += acc[i][j] * aS[j]; d += acc[i][j] * aD[j]; }
#pragma unroll
    for (int off = TX / 2; off; off >>= 1) {
      s += __shfl_xor(s, off);
      d += __shfl_xor(d, off);
    }
    if (tx == 0) {
      const int row = row0b + ty * RPTY + i;
      fsrc[row] = s;
      fdst[row] = d;
    }
  }
}

// ---------------------------------------------------------------------------
// K1: blocks [0,512) = L1 GAT GEMM (+coef1), blocks [512,2560) = edge build.
__global__ __launch_bounds__(256) void k1_gemm_edges(
    const float* __restrict__ x, const float* __restrict__ W1,
    const float* __restrict__ a1, float* __restrict__ Wh1,
    float* __restrict__ fs1, float* __restrict__ fd1,
    const float* __restrict__ adj, int* __restrict__ eidx,
    int* __restrict__ ecnt) {
  __shared__ float sA[32 * (64 + 4)];
  __shared__ float sB[32 * (64 + 4)];
  constexpr int NB_GEMM = (NN / 64) * NHEADS * NADJ;  // 512
  if (blockIdx.x < NB_GEMM) {
    int b = blockIdx.x;
    const int tile = b % (NN / 64); b /= (NN / 64);
    const int h = b % NHEADS;
    const int g = b / NHEADS;
    const int gh = g * NHEADS + h;
    gemm_body<NFEAT, NHID1, 4>(
        x, W1 + (size_t)gh * NFEAT * NHID1, Wh1 + (size_t)gh * NN * NHID1,
        a1 + (size_t)gh * 2 * NHID1, fs1 + (size_t)gh * NN,
        fd1 + (size_t)gh * NN, tile * 64, sA, sB);
  } else {
    const int wave = threadIdx.x >> 6;
    const int lane = threadIdx.x & 63;
    const int r = (blockIdx.x - NB_GEMM) * 4 + wave;  // g*NN + n
    const float4* row = (const float4*)(adj + (size_t)r * NN);
    int* out = eidx + (size_t)r * CAP;
    int base = 0;
    for (int c = 0; c < NN; c += 256) {
      const float4 v = row[(c >> 2) + lane];
      const int j0 = c + lane * 4;
      const float vt[4] = {v.x, v.y, v.z, v.w};
#pragma unroll
      for (int t = 0; t < 4; ++t) {
        const bool hit = vt[t] > 0.f;
        const unsigned long long m = __ballot(hit);
        if (hit) {
          const int pos = base + __popcll(m & ((1ull << lane) - 1ull));
          if (pos < CAP) out[pos] = j0 + t;
        }
        base += __popcll(m);
      }
    }
    if (lane == 0) ecnt[r] = base < CAP ? base : CAP;
  }
}

// ---------------------------------------------------------------------------
// K2: per block = 16 rows x one graph. Phase A: sparse softmax+aggregate+elu
// (L1, O=64) -> h1row LDS. Phase B: x1 = elu(h1 @ Wi1 + bi1) (K-tiled LDS).
// Phase C: Wh2row = x1 @ W2[g,h] (reg accum) -> global + coef2 via shfl fold.
__global__ __launch_bounds__(256) void k2_fused(
    const float* __restrict__ Wh1, const float* __restrict__ fs1,
    const float* __restrict__ fd1, const int* __restrict__ eidx,
    const int* __restrict__ ecnt, const float* __restrict__ Wi1,
    const float* __restrict__ bi1, const float* __restrict__ W2,
    const float* __restrict__ a2, float* __restrict__ Wh2,
    float* __restrict__ fs2, float* __restrict__ fd2) {
  __shared__ float h1row[16][256];   // aggregated+elu L1 output rows
  __shared__ float stage[8192];      // 32 KB: Wi1 tile (16KB) / W2 (32KB)
  __shared__ float x1row[16][68];    // padded (stride 68 spreads banks)
  __shared__ float wgt[4][CAP];
  __shared__ int midx[4][CAP];
  const int g = blockIdx.y;
  const int n0 = blockIdx.x * 16;
  const int wave = threadIdx.x >> 6;
  const int lane = threadIdx.x & 63;

  // ---- Phase A: wave handles rows wave*4..+4, all 4 heads
  for (int rr = 0; rr < 4; ++rr) {
    const int r = wave * 4 + rr;
    const int n = n0 + r;
    const int cnt = ecnt[g * NN + n];
    const int* ei = eidx + (size_t)(g * NN + n) * CAP;
    for (int j = lane; j < cnt; j += 64) midx[wave][j] = ei[j];
    for (int h = 0; h < 4; ++h) {
      const int gh = g * NHEADS + h;
      const float fsv = fs1[(size_t)gh * NN + n];
      const float* fdv = fd1 + (size_t)gh * NN;
      float mx = -3.4e38f;
      for (int j = lane; j < cnt; j += 64) {
        float e = fsv + fdv[midx[wave][j]];
        e = e > 0.f ? e : 0.2f * e;  // leaky relu
        wgt[wave][j] = e;
        mx = fmaxf(mx, e);
      }
      for (int off = 32; off; off >>= 1) mx = fmaxf(mx, __shfl_xor(mx, off));
      float sm = 0.f;
      for (int j = lane; j < cnt; j += 64) {
        const float w = __expf(wgt[wave][j] - mx);
        wgt[wave][j] = w;
        sm += w;
      }
      for (int off = 32; off; off >>= 1) sm += __shfl_xor(sm, off);
      // gather: 16 lanes per edge row (float4), 4 edges in flight, x4 unroll
      const float* WhH = Wh1 + (size_t)gh * NN * NHID1;
      const int sub = lane >> 4;
      const int c4 = (lane & 15) * 4;
      float4 a0 = {0, 0, 0, 0}, a1v = {0, 0, 0, 0}, a2v = {0, 0, 0, 0}, a3 = {0, 0, 0, 0};
#define GAT1(ACC, JJ)                                                        \
  {                                                                          \
    const float w_ = wgt[wave][JJ];                                          \
    const float4 v_ = *(const float4*)(WhH + (size_t)midx[wave][JJ] * NHID1 + c4); \
    ACC.x += w_ * v_.x; ACC.y += w_ * v_.y; ACC.z += w_ * v_.z; ACC.w += w_ * v_.w; \
  }
      int j = sub;
      for (; j + 12 < cnt; j += 16) {
        GAT1(a0, j); GAT1(a1v, j + 4); GAT1(a2v, j + 8); GAT1(a3, j + 12);
      }
      for (; j < cnt; j += 4) GAT1(a0, j);
#undef GAT1
      float4 acc;
      acc.x = (a0.x + a1v.x) + (a2v.x + a3.x);
      acc.y = (a0.y + a1v.y) + (a2v.y + a3.y);
      acc.z = (a0.z + a1v.z) + (a2v.z + a3.z);
      acc.w = (a0.w + a1v.w) + (a2v.w + a3.w);
#pragma unroll
      for (int off = 16; off < 64; off <<= 1) {
        acc.x += __shfl_xor(acc.x, off);
        acc.y += __shfl_xor(acc.y, off);
        acc.z += __shfl_xor(acc.z, off);
        acc.w += __shfl_xor(acc.w, off);
      }
      if (lane < 16) {
        const float inv = 1.f / sm;
        float4 o;
        o.x = acc.x * inv; o.y = acc.y * inv; o.z = acc.z * inv; o.w = acc.w * inv;
        o.x = o.x > 0.f ? o.x : (__expf(o.x) - 1.f);
        o.y = o.y > 0.f ? o.y : (__expf(o.y) - 1.f);
        o.z = o.z > 0.f ? o.z : (__expf(o.z) - 1.f);
        o.w = o.w > 0.f ? o.w : (__expf(o.w) - 1.f);
        *(float4*)&h1row[r][h * NHID1 + c4] = o;
      }
    }
  }

  // ---- Phase B: x1row = elu(h1row @ Wi1 + bi1), 4 rows/thread (own wave's rows)
  const int cB = threadIdx.x & 63;
  const int rgB = threadIdx.x >> 6;
  float accB[4] = {0.f, 0.f, 0.f, 0.f};
  for (int kt = 0; kt < 4; ++kt) {
    __syncthreads();
    const float4* src = (const float4*)(Wi1 + kt * 64 * 64);
    for (int i = threadIdx.x; i < 1024; i += 256) ((float4*)stage)[i] = src[i];
    __syncthreads();
    for (int k = 0; k < 64; ++k) {
      const float b = stage[k * 64 + cB];
#pragma unroll
      for (int i = 0; i < 4; ++i) accB[i] += h1row[rgB * 4 + i][kt * 64 + k] * b;
    }
  }
  const float bb = bi1[cB];
#pragma unroll
  for (int i = 0; i < 4; ++i) {
    float v = accB[i] + bb;
    x1row[rgB * 4 + i][cB] = v > 0.f ? v : (__expf(v) - 1.f);
  }

  // ---- Phase C: Wh2row = x1row @ W2[g,h]; coef2 via in-register shfl fold
  __syncthreads();
  const float4* w2src = (const float4*)(W2 + (size_t)g * NHEADS * NHID1 * NHID2);
  for (int i = threadIdx.x; i < 2048; i += 256) ((float4*)stage)[i] = w2src[i];
  __syncthreads();
  const int r3 = threadIdx.x >> 4;
  const int h3 = (threadIdx.x >> 2) & 3;
  const int c8q = threadIdx.x & 3;
  const int c8 = c8q * 8;
  const int gh3 = g * NHEADS + h3;
  float accC[8] = {0.f, 0.f, 0.f, 0.f, 0.f, 0.f, 0.f, 0.f};
  for (int k = 0; k < 64; ++k) {
    const float av = x1row[r3][k];
#pragma unroll
    for (int j = 0; j < 8; ++j) accC[j] += av * stage[(h3 * 64 + k) * 32 + c8 + j];
  }
  float4 o0, o1;
  o0.x = accC[0]; o0.y = accC[1]; o0.z = accC[2]; o0.w = accC[3];
  o1.x = accC[4]; o1.y = accC[5]; o1.z = accC[6]; o1.w = accC[7];
  float* wp = Wh2 + ((size_t)gh3 * NN + n0 + r3) * NHID2 + c8;
  *(float4*)wp = o0;
  *(float4*)(wp + 4) = o1;
  const float* aaS = a2 + ((size_t)gh3 * 2) * NHID2 + c8;
  const float* aaD = aaS + NHID2;
  float s = 0.f, d = 0.f;
#pragma unroll
  for (int j = 0; j < 8; ++j) { s += accC[j] * aaS[j]; d += accC[j] * aaD[j]; }
  s += __shfl_xor(s, 1); s += __shfl_xor(s, 2);
  d += __shfl_xor(d, 1); d += __shfl_xor(d, 2);
  if (c8q == 0) {
    fs2[(size_t)gh3 * NN + n0 + r3] = s;
    fd2[(size_t)gh3 * NN + n0 + r3] = d;
  }
}

// ---------------------------------------------------------------------------
// K3: per block = 8 rows x BOTH graphs. Phase A: L2 aggregate (O=32) + elu ->
// h2cat LDS. Phase B: o2 = elu(h2 @ Wi2 + bi2). Phase C: logits = cat @ Wf +
// bf, log_softmax, write; l1 in block 0.
__global__ __launch_bounds__(256) void k3_fused(
    const float* __restrict__ Wh2, const float* __restrict__ fs2,
    const float* __restrict__ fd2, const int* __restrict__ eidx,
    const int* __restrict__ ecnt, const float* __restrict__ Wi2,
    const float* __restrict__ bi2, const float* __restrict__ Wf,
    const float* __restrict__ bfv, float* __restrict__ out) {
  __shared__ float h2cat[8][260];     // [r][g*128 + h*32 + o], padded stride
  __shared__ float Wi2s[128 * 8];
  __shared__ float WfS[16 * 8];
  __shared__ float cat[8][17];
  __shared__ float wgt[4][CAP];
  __shared__ int midx[4][CAP];
  const int n0 = blockIdx.x * 8;
  const int wave = threadIdx.x >> 6;
  const int lane = threadIdx.x & 63;
  const int g = wave >> 1;

  for (int i = threadIdx.x; i < 256; i += 256) ((float4*)Wi2s)[i] = ((const float4*)Wi2)[i];
  if (threadIdx.x < 32) ((float4*)WfS)[threadIdx.x] = ((const float4*)Wf)[threadIdx.x];

  // ---- Phase A: wave handles rows (wave&1)*4..+4 of graph g, all heads
  for (int rr = 0; rr < 4; ++rr) {
    const int r = (wave & 1) * 4 + rr;
    const int n = n0 + r;
    const int cnt = ecnt[g * NN + n];
    const int* ei = eidx + (size_t)(g * NN + n) * CAP;
    for (int j = lane; j < cnt; j += 64) midx[wave][j] = ei[j];
    for (int h = 0; h < 4; ++h) {
      const int gh = g * NHEADS + h;
      const float fsv = fs2[(size_t)gh * NN + n];
      const float* fdv = fd2 + (size_t)gh * NN;
      float mx = -3.4e38f;
      for (int j = lane; j < cnt; j += 64) {
        float e = fsv + fdv[midx[wave][j]];
        e = e > 0.f ? e : 0.2f * e;
        wgt[wave][j] = e;
        mx = fmaxf(mx, e);
      }
      for (int off = 32; off; off >>= 1) mx = fmaxf(mx, __shfl_xor(mx, off));
      float sm = 0.f;
      for (int j = lane; j < cnt; j += 64) {
        const float w = __expf(wgt[wave][j] - mx);
        wgt[wave][j] = w;
        sm += w;
      }
      for (int off = 32; off; off >>= 1) sm += __shfl_xor(sm, off);
      // gather: 8 lanes per edge row (float4), 8 edges in flight, x4 unroll
      const float* WhH = Wh2 + (size_t)gh * NN * NHID2;
      const int sub = lane >> 3;
      const int c4 = (lane & 7) * 4;
      float4 a0 = {0, 0, 0, 0}, a1v = {0, 0, 0, 0}, a2v = {0, 0, 0, 0}, a3 = {0, 0, 0, 0};
#define GAT2(ACC, JJ)                                                        \
  {                                                                          \
    const float w_ = wgt[wave][JJ];                                          \
    const float4 v_ = *(const float4*)(WhH + (size_t)midx[wave][JJ] * NHID2 + c4); \
    ACC.x += w_ * v_.x; ACC.y += w_ * v_.y; ACC.z += w_ * v_.z; ACC.w += w_ * v_.w; \
  }
      int j = sub;
      for (; j + 24 < cnt; j += 32) {
        GAT2(a0, j); GAT2(a1v, j + 8); GAT2(a2v, j + 16); GAT2(a3, j + 24);
      }
      for (; j < cnt; j += 8) GAT2(a0, j);
#undef GAT2
      float4 acc;
      acc.x = (a0.x + a1v.x) + (a2v.x + a3.x);
      acc.y = (a0.y + a1v.y) + (a2v.y + a3.y);
      acc.z = (a0.z + a1v.z) + (a2v.z + a3.z);
      acc.w = (a0.w + a1v.w) + (a2v.w + a3.w);
#pragma unroll
      for (int off = 8; off < 64; off <<= 1) {
        acc.x += __shfl_xor(acc.x, off);
        acc.y += __shfl_xor(acc.y, off);
        acc.z += __shfl_xor(acc.z, off);
        acc.w += __shfl_xor(acc.w, off);
      }
      if (lane < 8) {
        const float inv = 1.f / sm;
        float4 o;
        o.x = acc.x * inv; o.y = acc.y * inv; o.z = acc.z * inv; o.w = acc.w * inv;
        o.x = o.x > 0.f ? o.x : (__expf(o.x) - 1.f);
        o.y = o.y > 0.f ? o.y : (__expf(o.y) - 1.f);
        o.z = o.z > 0.f ? o.z : (__expf(o.z) - 1.f);
        o.w = o.w > 0.f ? o.w : (__expf(o.w) - 1.f);
        *(float4*)&h2cat[r][g * 128 + h * NHID2 + c4] = o;
      }
    }
  }
  __syncthreads();

  // ---- Phase B: o2cat
  if (threadIdx.x < 128) {
    const int r = threadIdx.x >> 4;
    const int gg = (threadIdx.x >> 3) & 1;
    const int c = threadIdx.x & 7;
    float s = bi2[c];
    for (int k = 0; k < 128; ++k) s += h2cat[r][gg * 128 + k] * Wi2s[k * 8 + c];
    cat[r][gg * 8 + c] = s > 0.f ? s : (__expf(s) - 1.f);
  }
  __syncthreads();

  // ---- Phase C: logits + log_softmax
  if (threadIdx.x < 64) {
    const int r = threadIdx.x >> 3;
    const int c = threadIdx.x & 7;
    float logit = bfv[c];
#pragma unroll
    for (int k = 0; k < 16; ++k) logit += cat[r][k] * WfS[k * 8 + c];
    float m = logit;
#pragma unroll
    for (int off = 4; off; off >>= 1) m = fmaxf(m, __shfl_xor(m, off));
    float s = __expf(logit - m);
#pragma unroll
    for (int off = 4; off; off >>= 1) s += __shfl_xor(s, off);
    out[(size_t)(n0 + r) * NCLASS + c] = logit - (logf(s) + m);
  }
  if (blockIdx.x == 0 && threadIdx.x < 64) {
    float v = fabsf(Wf[threadIdx.x]) + fabsf(Wf[64 + threadIdx.x]);
    for (int off = 32; off; off >>= 1) v += __shfl_xor(v, off);
    if (threadIdx.x == 0) out[NN * NCLASS] = v * (1.f / (2 * NCLASS * NCLASS));
  }
}

// ---------------------------------------------------------------------------
extern "C" void kernel_launch(void* const* d_in, const int* in_sizes, int n_in,
                              void* d_out, int out_size, void* d_ws, size_t ws_size,
                              hipStream_t stream) {
  const float* x = (const float*)d_in[0];
  const float* adj = (const float*)d_in[1];
  const float* W1 = (const float*)d_in[2];
  const float* a1 = (const float*)d_in[3];
  const float* W2 = (const float*)d_in[4];
  const float* a2 = (const float*)d_in[5];
  const float* Wi1 = (const float*)d_in[6];
  const float* bi1 = (const float*)d_in[7];
  const float* Wi2 = (const float*)d_in[8];
  const float* bi2 = (const float*)d_in[9];
  const float* Wf = (const float*)d_in[10];
  const float* bfv = (const float*)d_in[11];
  float* out = (float*)d_out;

  char* ws = (char*)d_ws;
  int* eidx = (int*)ws;     ws += (size_t)NADJ * NN * CAP * 4;             // 4 MB
  int* ecnt = (int*)ws;     ws += (size_t)NADJ * NN * 4;
  float* Wh1 = (float*)ws;  ws += (size_t)NADJ * NHEADS * NN * NHID1 * 4;  // 8 MB
  float* fs1 = (float*)ws;  ws += (size_t)NADJ * NHEADS * NN * 4;
  float* fd1 = (float*)ws;  ws += (size_t)NADJ * NHEADS * NN * 4;
  float* Wh2 = (float*)ws;  ws += (size_t)NADJ * NHEADS * NN * NHID2 * 4;  // 4 MB
  float* fs2 = (float*)ws;  ws += (size_t)NADJ * NHEADS * NN * 4;
  float* fd2 = (float*)ws;  ws += (size_t)NADJ * NHEADS * NN * 4;

  // K1: L1 GEMM(+coef1) overlapped with edge-list build.
  k1_gemm_edges<<<512 + NADJ * NN / 4, 256, 0, stream>>>(
      x, W1, a1, Wh1, fs1, fd1, adj, eidx, ecnt);

  // K2: L1 aggregate + interlayer + L2 GEMM + coef2.
  k2_fused<<<dim3(NN / 16, NADJ), 256, 0, stream>>>(
      Wh1, fs1, fd1, eidx, ecnt, Wi1, bi1, W2, a2, Wh2, fs2, fd2);

  // K3: L2 aggregate + Wi2 + concat + Wf + log_softmax + l1.
  k3_fused<<<NN / 8, 256, 0, stream>>>(
      Wh2, fs2, fd2, eidx, ecnt, Wi2, bi2, Wf, bfv, out);
}

// Round 8
// 142.042 us; speedup vs baseline: 1.0647x; 1.0647x over previous
//
#include <hip/hip_runtime.h>
#include <hip/hip_bf16.h>

#define NN 4096
#define NFEAT 256
#define NHID1 64
#define NHID2 32
#define NCLASS 8
#define NHEADS 4
#define NADJ 2
#define CAP 128

// ---------------------------------------------------------------------------
// Register-blocked tiled GEMM body (k1): C = A @ B, fused attention coefs.
template <int KDIM, int NDIM, int RPTY>
__device__ __forceinline__ void gemm_body(
    const float* __restrict__ A, const float* __restrict__ B,
    float* __restrict__ C, const float* __restrict__ ag,
    float* __restrict__ fsrc, float* __restrict__ fdst, const int row0b,
    float* __restrict__ sA, float* __restrict__ sB) {
  constexpr int KT = 32;
  constexpr int TX = NDIM / 4;
  constexpr int TY = 256 / TX;
  constexpr int BR = TY * RPTY;
  constexpr int LDA = BR + 4;
  constexpr int LDB = NDIM + 4;
  const int tid = threadIdx.x;
  const int tx = tid % TX, ty = tid / TX;
  const int c0 = tx * 4;
  float acc[RPTY][4];
#pragma unroll
  for (int i = 0; i < RPTY; ++i)
#pragma unroll
    for (int j = 0; j < 4; ++j) acc[i][j] = 0.f;

  for (int kt = 0; kt < KDIM; kt += KT) {
    __syncthreads();
    for (int i = tid; i < BR * (KT / 4); i += 256) {
      const int r = i / (KT / 4), e = i % (KT / 4);
      const float4 v = *(const float4*)(A + (size_t)(row0b + r) * KDIM + kt + e * 4);
      sA[(e * 4 + 0) * LDA + r] = v.x;
      sA[(e * 4 + 1) * LDA + r] = v.y;
      sA[(e * 4 + 2) * LDA + r] = v.z;
      sA[(e * 4 + 3) * LDA + r] = v.w;
    }
    for (int i = tid; i < KT * (NDIM / 4); i += 256) {
      const int k = i / (NDIM / 4), cc = i % (NDIM / 4);
      *(float4*)&sB[k * LDB + cc * 4] = *(const float4*)(B + (size_t)(kt + k) * NDIM + cc * 4);
    }
    __syncthreads();
#pragma unroll
    for (int k = 0; k < KT; ++k) {
      const float4 t = *(const float4*)&sA[k * LDA + ty * 4];
      const float a4[4] = {t.x, t.y, t.z, t.w};
      const float4 bv = *(const float4*)&sB[k * LDB + c0];
      const float b4[4] = {bv.x, bv.y, bv.z, bv.w};
#pragma unroll
      for (int i = 0; i < RPTY; ++i)
#pragma unroll
        for (int j = 0; j < 4; ++j) acc[i][j] += a4[i] * b4[j];
    }
  }
#pragma unroll
  for (int i = 0; i < RPTY; ++i) {
    const int row = row0b + ty * RPTY + i;
    float4 o;
    o.x = acc[i][0]; o.y = acc[i][1]; o.z = acc[i][2]; o.w = acc[i][3];
    *(float4*)&C[(size_t)row * NDIM + c0] = o;
  }
  float aS[4], aD[4];
#pragma unroll
  for (int j = 0; j < 4; ++j) { aS[j] = ag[c0 + j]; aD[j] = ag[NDIM + c0 + j]; }
#pragma unroll
  for (int i = 0; i < RPTY; ++i) {
    float s = 0.f, d = 0.f;
#pragma unroll
    for (int j = 0; j < 4; ++j) { s += acc[i][j] * aS[j]; d += acc[i][j] * aD[j]; }
#pragma unroll
    for (int off = TX / 2; off; off >>= 1) {
      s += __shfl_xor(s, off);
      d += __shfl_xor(d, off);
    }
    if (tx == 0) {
      const int row = row0b + ty * RPTY + i;
      fsrc[row] = s;
      fdst[row] = d;
    }
  }
}

// ---------------------------------------------------------------------------
// K1: blocks [0,512) = L1 GAT GEMM (+coef1), blocks [512,2560) = edge build.
__global__ __launch_bounds__(256) void k1_gemm_edges(
    const float* __restrict__ x, const float* __restrict__ W1,
    const float* __restrict__ a1, float* __restrict__ Wh1,
    float* __restrict__ fs1, float* __restrict__ fd1,
    const float* __restrict__ adj, int* __restrict__ eidx,
    int* __restrict__ ecnt) {
  __shared__ float sA[32 * (64 + 4)];
  __shared__ float sB[32 * (64 + 4)];
  constexpr int NB_GEMM = (NN / 64) * NHEADS * NADJ;  // 512
  if (blockIdx.x < NB_GEMM) {
    int b = blockIdx.x;
    const int tile = b % (NN / 64); b /= (NN / 64);
    const int h = b % NHEADS;
    const int g = b / NHEADS;
    const int gh = g * NHEADS + h;
    gemm_body<NFEAT, NHID1, 4>(
        x, W1 + (size_t)gh * NFEAT * NHID1, Wh1 + (size_t)gh * NN * NHID1,
        a1 + (size_t)gh * 2 * NHID1, fs1 + (size_t)gh * NN,
        fd1 + (size_t)gh * NN, tile * 64, sA, sB);
  } else {
    const int wave = threadIdx.x >> 6;
    const int lane = threadIdx.x & 63;
    const int r = (blockIdx.x - NB_GEMM) * 4 + wave;  // g*NN + n
    const float4* row = (const float4*)(adj + (size_t)r * NN);
    int* out = eidx + (size_t)r * CAP;
    int base = 0;
    for (int c = 0; c < NN; c += 256) {
      const float4 v = row[(c >> 2) + lane];
      const int j0 = c + lane * 4;
      const float vt[4] = {v.x, v.y, v.z, v.w};
#pragma unroll
      for (int t = 0; t < 4; ++t) {
        const bool hit = vt[t] > 0.f;
        const unsigned long long m = __ballot(hit);
        if (hit) {
          const int pos = base + __popcll(m & ((1ull << lane) - 1ull));
          if (pos < CAP) out[pos] = j0 + t;
        }
        base += __popcll(m);
      }
    }
    if (lane == 0) ecnt[r] = base < CAP ? base : CAP;
  }
}

// ---------------------------------------------------------------------------
// K2: block = 2 rows x 1 graph, 8 waves; wave = one (row, head) for phase A
// (same per-wave work as the fast round-6 aggregate). Then x1 = elu(h1@Wi1+b)
// and Wh2 = x1@W2 (+coef2) in-block; h1/x1 never touch global.
__global__ __launch_bounds__(512) void k2_fused(
    const float* __restrict__ Wh1, const float* __restrict__ fs1,
    const float* __restrict__ fd1, const int* __restrict__ eidx,
    const int* __restrict__ ecnt, const float* __restrict__ Wi1,
    const float* __restrict__ bi1, const float* __restrict__ W2,
    const float* __restrict__ a2, float* __restrict__ Wh2,
    float* __restrict__ fs2, float* __restrict__ fd2) {
  __shared__ float Wi1s[64 * 64];           // 16 KB
  __shared__ float W2s[NHEADS * 64 * 32];   // 32 KB
  __shared__ float h1row[2][256];
  __shared__ float x1row[2][68];
  __shared__ float partB[2][4][68];
  __shared__ float wgt[8][CAP];
  __shared__ int midx[2][CAP];
  const int g = blockIdx.y;
  const int n0 = blockIdx.x * 2;
  const int tid = threadIdx.x;
  const int wave = tid >> 6;
  const int lane = tid & 63;

  // stage weights + edge lists
  for (int i = tid; i < 1024; i += 512) ((float4*)Wi1s)[i] = ((const float4*)Wi1)[i];
  {
    const float4* w2src = (const float4*)(W2 + (size_t)g * NHEADS * 64 * 32);
    for (int i = tid; i < 2048; i += 512) ((float4*)W2s)[i] = w2src[i];
  }
  for (int i = tid; i < 2 * CAP; i += 512) {
    const int r_ = i >> 7, j = i & (CAP - 1);
    midx[r_][j] = eidx[(size_t)(g * NN + n0 + r_) * CAP + j];
  }
  __syncthreads();

  // ---- Phase A: wave = (r, h); one sparse softmax+gather per wave
  {
    const int r = wave >> 2;
    const int h = wave & 3;
    const int n = n0 + r;
    const int gh = g * NHEADS + h;
    const int cnt = ecnt[g * NN + n];
    const float fsv = fs1[(size_t)gh * NN + n];
    const float* fdv = fd1 + (size_t)gh * NN;
    float mx = -3.4e38f;
    for (int j = lane; j < cnt; j += 64) {
      float e = fsv + fdv[midx[r][j]];
      e = e > 0.f ? e : 0.2f * e;  // leaky relu alpha=0.2
      wgt[wave][j] = e;
      mx = fmaxf(mx, e);
    }
    for (int off = 32; off; off >>= 1) mx = fmaxf(mx, __shfl_xor(mx, off));
    float sm = 0.f;
    for (int j = lane; j < cnt; j += 64) {
      const float w = __expf(wgt[wave][j] - mx);
      wgt[wave][j] = w;
      sm += w;
    }
    for (int off = 32; off; off >>= 1) sm += __shfl_xor(sm, off);
    // gather: 16 lanes/edge-row (float4), 4 edges in parallel, x4 unroll
    const float* WhH = Wh1 + (size_t)gh * NN * NHID1;
    const int sub = lane >> 4;
    const int c4 = (lane & 15) * 4;
    float4 a0 = {0, 0, 0, 0}, a1v = {0, 0, 0, 0}, a2v = {0, 0, 0, 0}, a3 = {0, 0, 0, 0};
#define GAT1(ACC, JJ)                                                         \
  {                                                                           \
    const float w_ = wgt[wave][JJ];                                           \
    const float4 v_ = *(const float4*)(WhH + (size_t)midx[r][JJ] * NHID1 + c4); \
    ACC.x += w_ * v_.x; ACC.y += w_ * v_.y; ACC.z += w_ * v_.z; ACC.w += w_ * v_.w; \
  }
    int j = sub;
    for (; j + 12 < cnt; j += 16) {
      GAT1(a0, j); GAT1(a1v, j + 4); GAT1(a2v, j + 8); GAT1(a3, j + 12);
    }
    for (; j < cnt; j += 4) GAT1(a0, j);
#undef GAT1
    float4 acc;
    acc.x = (a0.x + a1v.x) + (a2v.x + a3.x);
    acc.y = (a0.y + a1v.y) + (a2v.y + a3.y);
    acc.z = (a0.z + a1v.z) + (a2v.z + a3.z);
    acc.w = (a0.w + a1v.w) + (a2v.w + a3.w);
#pragma unroll
    for (int off = 16; off < 64; off <<= 1) {
      acc.x += __shfl_xor(acc.x, off);
      acc.y += __shfl_xor(acc.y, off);
      acc.z += __shfl_xor(acc.z, off);
      acc.w += __shfl_xor(acc.w, off);
    }
    if (lane < 16) {
      const float inv = 1.f / sm;
      float4 o;
      o.x = acc.x * inv; o.y = acc.y * inv; o.z = acc.z * inv; o.w = acc.w * inv;
      o.x = o.x > 0.f ? o.x : (__expf(o.x) - 1.f);
      o.y = o.y > 0.f ? o.y : (__expf(o.y) - 1.f);
      o.z = o.z > 0.f ? o.z : (__expf(o.z) - 1.f);
      o.w = o.w > 0.f ? o.w : (__expf(o.w) - 1.f);
      *(float4*)&h1row[r][h * NHID1 + c4] = o;
    }
  }
  __syncthreads();

  // ---- Phase B: x1row = elu(h1row @ Wi1 + bi1); k-split over 4 chunks
  {
    const int c = tid & 63;
    const int kc = (tid >> 6) & 3;
    const int r = tid >> 8;
    float s = 0.f;
#pragma unroll 8
    for (int k = kc * 64; k < kc * 64 + 64; ++k) s += h1row[r][k] * Wi1s[k * 64 + c];
    partB[r][kc][c] = s;
  }
  __syncthreads();
  if (tid < 128) {
    const int r = tid >> 6, c = tid & 63;
    float v = partB[r][0][c] + partB[r][1][c] + partB[r][2][c] + partB[r][3][c] + bi1[c];
    x1row[r][c] = v > 0.f ? v : (__expf(v) - 1.f);
  }
  __syncthreads();

  // ---- Phase C: Wh2 = x1row @ W2[h] (+coef2); wave = (r,h), lanes = kh x c
  {
    const int r = tid >> 8;
    const int h = (tid >> 6) & 3;
    const int kh = (tid >> 5) & 1;
    const int c = tid & 31;
    const int gh = g * NHEADS + h;
    const int n = n0 + r;
    float acc = 0.f;
#pragma unroll 8
    for (int k = kh * 32; k < kh * 32 + 32; ++k)
      acc += x1row[r][k] * W2s[(h * 64 + k) * 32 + c];
    acc += __shfl_xor(acc, 32);  // fold k-halves
    if (kh == 0) Wh2[((size_t)gh * NN + n) * NHID2 + c] = acc;
    const float aS = a2[(size_t)gh * 2 * NHID2 + c];
    const float aD = a2[(size_t)gh * 2 * NHID2 + NHID2 + c];
    float s = acc * aS, d = acc * aD;
#pragma unroll
    for (int off = 16; off; off >>= 1) {
      s += __shfl_xor(s, off);
      d += __shfl_xor(d, off);
    }
    if (kh == 0 && c == 0) {
      fs2[(size_t)gh * NN + n] = s;
      fd2[(size_t)gh * NN + n] = d;
    }
  }
}

// ---------------------------------------------------------------------------
// K3: block = 1 row, 8 waves = (graph, head); phase A = L2 aggregate (one
// (n,g,h) per wave), then Wi2 + concat + Wf + log_softmax in-block.
__global__ __launch_bounds__(512) void k3_fused(
    const float* __restrict__ Wh2, const float* __restrict__ fs2,
    const float* __restrict__ fd2, const int* __restrict__ eidx,
    const int* __restrict__ ecnt, const float* __restrict__ Wi2,
    const float* __restrict__ bi2, const float* __restrict__ Wf,
    const float* __restrict__ bfv, float* __restrict__ out) {
  __shared__ float Wi2s[128 * 8];   // 4 KB
  __shared__ float WfS[16 * 8];
  __shared__ float h2cat[260];
  __shared__ float cat[17];
  __shared__ float wgt[8][CAP];
  __shared__ int midx[2][CAP];
  const int n = blockIdx.x;
  const int tid = threadIdx.x;
  const int wave = tid >> 6;
  const int lane = tid & 63;

  for (int i = tid; i < 256; i += 512) ((float4*)Wi2s)[i] = ((const float4*)Wi2)[i];
  if (tid < 32) ((float4*)WfS)[tid] = ((const float4*)Wf)[tid];
  for (int i = tid; i < 2 * CAP; i += 512) {
    const int g_ = i >> 7, j = i & (CAP - 1);
    midx[g_][j] = eidx[(size_t)(g_ * NN + n) * CAP + j];
  }
  __syncthreads();

  // ---- Phase A: wave = (g, h)
  {
    const int g = wave >> 2;
    const int h = wave & 3;
    const int gh = g * NHEADS + h;
    const int cnt = ecnt[g * NN + n];
    const float fsv = fs2[(size_t)gh * NN + n];
    const float* fdv = fd2 + (size_t)gh * NN;
    float mx = -3.4e38f;
    for (int j = lane; j < cnt; j += 64) {
      float e = fsv + fdv[midx[g][j]];
      e = e > 0.f ? e : 0.2f * e;
      wgt[wave][j] = e;
      mx = fmaxf(mx, e);
    }
    for (int off = 32; off; off >>= 1) mx = fmaxf(mx, __shfl_xor(mx, off));
    float sm = 0.f;
    for (int j = lane; j < cnt; j += 64) {
      const float w = __expf(wgt[wave][j] - mx);
      wgt[wave][j] = w;
      sm += w;
    }
    for (int off = 32; off; off >>= 1) sm += __shfl_xor(sm, off);
    // gather: 8 lanes/edge-row (float4), 8 edges in parallel, x4 unroll
    const float* WhH = Wh2 + (size_t)gh * NN * NHID2;
    const int sub = lane >> 3;
    const int c4 = (lane & 7) * 4;
    float4 a0 = {0, 0, 0, 0}, a1v = {0, 0, 0, 0}, a2v = {0, 0, 0, 0}, a3 = {0, 0, 0, 0};
#define GAT2(ACC, JJ)                                                         \
  {                                                                           \
    const float w_ = wgt[wave][JJ];                                           \
    const float4 v_ = *(const float4*)(WhH + (size_t)midx[g][JJ] * NHID2 + c4); \
    ACC.x += w_ * v_.x; ACC.y += w_ * v_.y; ACC.z += w_ * v_.z; ACC.w += w_ * v_.w; \
  }
    int j = sub;
    for (; j + 24 < cnt; j += 32) {
      GAT2(a0, j); GAT2(a1v, j + 8); GAT2(a2v, j + 16); GAT2(a3, j + 24);
    }
    for (; j < cnt; j += 8) GAT2(a0, j);
#undef GAT2
    float4 acc;
    acc.x = (a0.x + a1v.x) + (a2v.x + a3.x);
    acc.y = (a0.y + a1v.y) + (a2v.y + a3.y);
    acc.z = (a0.z + a1v.z) + (a2v.z + a3.z);
    acc.w = (a0.w + a1v.w) + (a2v.w + a3.w);
#pragma unroll
    for (int off = 8; off < 64; off <<= 1) {
      acc.x += __shfl_xor(acc.x, off);
      acc.y += __shfl_xor(acc.y, off);
      acc.z += __shfl_xor(acc.z, off);
      acc.w += __shfl_xor(acc.w, off);
    }
    if (lane < 8) {
      const float inv = 1.f / sm;
      float4 o;
      o.x = acc.x * inv; o.y = acc.y * inv; o.z = acc.z * inv; o.w = acc.w * inv;
      o.x = o.x > 0.f ? o.x : (__expf(o.x) - 1.f);
      o.y = o.y > 0.f ? o.y : (__expf(o.y) - 1.f);
      o.z = o.z > 0.f ? o.z : (__expf(o.z) - 1.f);
      o.w = o.w > 0.f ? o.w : (__expf(o.w) - 1.f);
      *(float4*)&h2cat[g * 128 + h * NHID2 + c4] = o;
    }
  }
  __syncthreads();

  // ---- Phase B: cat = elu(h2cat @ Wi2 + bi2) per graph; k-split 32x4
  {
    const int gg = tid >> 8;
    const int c = (tid >> 5) & 7;
    const int kc = tid & 31;
    float s = 0.f;
#pragma unroll
    for (int k = kc * 4; k < kc * 4 + 4; ++k) s += h2cat[gg * 128 + k] * Wi2s[k * 8 + c];
#pragma unroll
    for (int off = 16; off; off >>= 1) s += __shfl_xor(s, off);
    if (kc == 0) {
      const float v = s + bi2[c];
      cat[gg * 8 + c] = v > 0.f ? v : (__expf(v) - 1.f);
    }
  }
  __syncthreads();

  // ---- Phase C: logits + log_softmax (8 lanes)
  if (tid < 8) {
    const int c = tid;
    float logit = bfv[c];
#pragma unroll
    for (int k = 0; k < 16; ++k) logit += cat[k] * WfS[k * 8 + c];
    float m = logit;
#pragma unroll
    for (int off = 4; off; off >>= 1) m = fmaxf(m, __shfl_xor(m, off));
    float s = __expf(logit - m);
#pragma unroll
    for (int off = 4; off; off >>= 1) s += __shfl_xor(s, off);
    out[(size_t)n * NCLASS + c] = logit - (logf(s) + m);
  }
  if (blockIdx.x == 0 && tid >= 64 && tid < 128) {
    const int t = tid - 64;
    float v = fabsf(Wf[t]) + fabsf(Wf[64 + t]);
    for (int off = 32; off; off >>= 1) v += __shfl_xor(v, off);
    if (t == 0) out[NN * NCLASS] = v * (1.f / (2 * NCLASS * NCLASS));
  }
}

// ---------------------------------------------------------------------------
extern "C" void kernel_launch(void* const* d_in, const int* in_sizes, int n_in,
                              void* d_out, int out_size, void* d_ws, size_t ws_size,
                              hipStream_t stream) {
  const float* x = (const float*)d_in[0];
  const float* adj = (const float*)d_in[1];
  const float* W1 = (const float*)d_in[2];
  const float* a1 = (const float*)d_in[3];
  const float* W2 = (const float*)d_in[4];
  const float* a2 = (const float*)d_in[5];
  const float* Wi1 = (const float*)d_in[6];
  const float* bi1 = (const float*)d_in[7];
  const float* Wi2 = (const float*)d_in[8];
  const float* bi2 = (const float*)d_in[9];
  const float* Wf = (const float*)d_in[10];
  const float* bfv = (const float*)d_in[11];
  float* out = (float*)d_out;

  char* ws = (char*)d_ws;
  int* eidx = (int*)ws;     ws += (size_t)NADJ * NN * CAP * 4;             // 4 MB
  int* ecnt = (int*)ws;     ws += (size_t)NADJ * NN * 4;
  float* Wh1 = (float*)ws;  ws += (size_t)NADJ * NHEADS * NN * NHID1 * 4;  // 8 MB
  float* fs1 = (float*)ws;  ws += (size_t)NADJ * NHEADS * NN * 4;
  float* fd1 = (float*)ws;  ws += (size_t)NADJ * NHEADS * NN * 4;
  float* Wh2 = (float*)ws;  ws += (size_t)NADJ * NHEADS * NN * NHID2 * 4;  // 4 MB
  float* fs2 = (float*)ws;  ws += (size_t)NADJ * NHEADS * NN * 4;
  float* fd2 = (float*)ws;  ws += (size_t)NADJ * NHEADS * NN * 4;

  // K1: L1 GEMM(+coef1) overlapped with edge-list build.
  k1_gemm_edges<<<512 + NADJ * NN / 4, 256, 0, stream>>>(
      x, W1, a1, Wh1, fs1, fd1, adj, eidx, ecnt);

  // K2: L1 aggregate (1 (n,h)/wave) + interlayer + L2 GEMM + coef2.
  k2_fused<<<dim3(NN / 2, NADJ), 512, 0, stream>>>(
      Wh1, fs1, fd1, eidx, ecnt, Wi1, bi1, W2, a2, Wh2, fs2, fd2);

  // K3: L2 aggregate (1 (n,g,h)/wave) + Wi2 + concat + Wf + log_softmax + l1.
  k3_fused<<<NN, 512, 0, stream>>>(
      Wh2, fs2, fd2, eidx, ecnt, Wi2, bi2, Wf, bfv, out);
}

// Round 9
// 101.272 us; speedup vs baseline: 1.4933x; 1.4026x over previous
//
#include <hip/hip_runtime.h>
#include <hip/hip_bf16.h>

#define NN 4096
#define NFEAT 256
#define NHID1 64
#define NHID2 32
#define NCLASS 8
#define NHEADS 4
#define NADJ 2
#define CAP 128

// f32 -> bf16 with round-to-nearest-even (bit trick, no lib dependence)
__device__ __forceinline__ unsigned short f2bf(float v) {
  unsigned int x = __float_as_uint(v);
  return (unsigned short)((x + 0x7fffu + ((x >> 16) & 1u)) >> 16);
}

// ---------------------------------------------------------------------------
// Register-blocked tiled GEMM body: C = act(A @ B + bias); optional fused
// attention coefs from the f32 accumulators; optional bf16 output.
template <int KDIM, int NDIM, int RPTY, int ACT, int COEF, int OBF16>
__device__ __forceinline__ void gemm_body(
    const float* __restrict__ A, const float* __restrict__ B,
    const float* __restrict__ bias, void* __restrict__ C,
    const float* __restrict__ ag, float* __restrict__ fsrc,
    float* __restrict__ fdst, const int row0b,
    float* __restrict__ sA, float* __restrict__ sB) {
  constexpr int KT = 32;
  constexpr int TX = NDIM / 4;
  constexpr int TY = 256 / TX;
  constexpr int BR = TY * RPTY;
  constexpr int LDA = BR + 4;
  constexpr int LDB = NDIM + 4;
  const int tid = threadIdx.x;
  const int tx = tid % TX, ty = tid / TX;
  const int c0 = tx * 4;
  float acc[RPTY][4];
#pragma unroll
  for (int i = 0; i < RPTY; ++i)
#pragma unroll
    for (int j = 0; j < 4; ++j) acc[i][j] = 0.f;

  for (int kt = 0; kt < KDIM; kt += KT) {
    __syncthreads();
    for (int i = tid; i < BR * (KT / 4); i += 256) {
      const int r = i / (KT / 4), e = i % (KT / 4);
      const float4 v = *(const float4*)(A + (size_t)(row0b + r) * KDIM + kt + e * 4);
      sA[(e * 4 + 0) * LDA + r] = v.x;
      sA[(e * 4 + 1) * LDA + r] = v.y;
      sA[(e * 4 + 2) * LDA + r] = v.z;
      sA[(e * 4 + 3) * LDA + r] = v.w;
    }
    for (int i = tid; i < KT * (NDIM / 4); i += 256) {
      const int k = i / (NDIM / 4), cc = i % (NDIM / 4);
      *(float4*)&sB[k * LDB + cc * 4] = *(const float4*)(B + (size_t)(kt + k) * NDIM + cc * 4);
    }
    __syncthreads();
#pragma unroll
    for (int k = 0; k < KT; ++k) {
      float a4[RPTY];
      if constexpr (RPTY == 4) {
        const float4 t = *(const float4*)&sA[k * LDA + ty * 4];
        a4[0] = t.x; a4[1] = t.y; a4[2] = t.z; a4[3] = t.w;
      } else {
        const float2 t = *(const float2*)&sA[k * LDA + ty * 2];
        a4[0] = t.x; a4[1] = t.y;
      }
      const float4 bv = *(const float4*)&sB[k * LDB + c0];
      const float b4[4] = {bv.x, bv.y, bv.z, bv.w};
#pragma unroll
      for (int i = 0; i < RPTY; ++i)
#pragma unroll
        for (int j = 0; j < 4; ++j) acc[i][j] += a4[i] * b4[j];
    }
  }
  float b4[4] = {0.f, 0.f, 0.f, 0.f};
  if (bias) {
    const float4 bb = *(const float4*)&bias[c0];
    b4[0] = bb.x; b4[1] = bb.y; b4[2] = bb.z; b4[3] = bb.w;
  }
#pragma unroll
  for (int i = 0; i < RPTY; ++i) {
    const int row = row0b + ty * RPTY + i;
    float v[4];
#pragma unroll
    for (int j = 0; j < 4; ++j) {
      v[j] = acc[i][j] + b4[j];
      if (ACT == 1) v[j] = v[j] > 0.f ? v[j] : (__expf(v[j]) - 1.f);  // elu
    }
    if constexpr (OBF16) {
      ushort4 o;
      o.x = f2bf(v[0]); o.y = f2bf(v[1]); o.z = f2bf(v[2]); o.w = f2bf(v[3]);
      *(ushort4*)((unsigned short*)C + (size_t)row * NDIM + c0) = o;
    } else {
      float4 o;
      o.x = v[0]; o.y = v[1]; o.z = v[2]; o.w = v[3];
      *(float4*)((float*)C + (size_t)row * NDIM + c0) = o;
    }
  }
  if constexpr (COEF) {
    float aS[4], aD[4];
#pragma unroll
    for (int j = 0; j < 4; ++j) { aS[j] = ag[c0 + j]; aD[j] = ag[NDIM + c0 + j]; }
#pragma unroll
    for (int i = 0; i < RPTY; ++i) {
      float s = 0.f, d = 0.f;
#pragma unroll
      for (int j = 0; j < 4; ++j) { s += acc[i][j] * aS[j]; d += acc[i][j] * aD[j]; }
#pragma unroll
      for (int off = TX / 2; off; off >>= 1) {
        s += __shfl_xor(s, off);
        d += __shfl_xor(d, off);
      }
      if (tx == 0) {
        const int row = row0b + ty * RPTY + i;
        fsrc[row] = s;
        fdst[row] = d;
      }
    }
  }
}

// ---------------------------------------------------------------------------
// K1: blocks [0,512) = L1 GAT GEMM (+coef1, bf16 Wh1); rest = edge build.
__global__ __launch_bounds__(256) void k1_gemm_edges(
    const float* __restrict__ x, const float* __restrict__ W1,
    const float* __restrict__ a1, unsigned short* __restrict__ Wh1,
    float* __restrict__ fs1, float* __restrict__ fd1,
    const float* __restrict__ adj, int* __restrict__ eidx,
    int* __restrict__ ecnt) {
  __shared__ float sA[32 * (64 + 4)];
  __shared__ float sB[32 * (64 + 4)];
  constexpr int NB_GEMM = (NN / 64) * NHEADS * NADJ;  // 512
  if (blockIdx.x < NB_GEMM) {
    int b = blockIdx.x;
    const int tile = b % (NN / 64); b /= (NN / 64);
    const int h = b % NHEADS;
    const int g = b / NHEADS;
    const int gh = g * NHEADS + h;
    gemm_body<NFEAT, NHID1, 4, 0, 1, 1>(
        x, W1 + (size_t)gh * NFEAT * NHID1, nullptr,
        Wh1 + (size_t)gh * NN * NHID1, a1 + (size_t)gh * 2 * NHID1,
        fs1 + (size_t)gh * NN, fd1 + (size_t)gh * NN, tile * 64, sA, sB);
  } else {
    const int wave = threadIdx.x >> 6;
    const int lane = threadIdx.x & 63;
    const int r = (blockIdx.x - NB_GEMM) * 4 + wave;  // g*NN + n
    const float4* row = (const float4*)(adj + (size_t)r * NN);
    int* out = eidx + (size_t)r * CAP;
    int base = 0;
    for (int c = 0; c < NN; c += 256) {
      const float4 v = row[(c >> 2) + lane];
      const int j0 = c + lane * 4;
      const float vt[4] = {v.x, v.y, v.z, v.w};
#pragma unroll
      for (int t = 0; t < 4; ++t) {
        const bool hit = vt[t] > 0.f;
        const unsigned long long m = __ballot(hit);
        if (hit) {
          const int pos = base + __popcll(m & ((1ull << lane) - 1ull));
          if (pos < CAP) out[pos] = j0 + t;
        }
        base += __popcll(m);
      }
    }
    if (lane == 0) ecnt[r] = base < CAP ? base : CAP;
  }
}

// ---------------------------------------------------------------------------
// Standalone GEMM wrapper.
template <int KDIM, int NDIM, int RPTY, int ACT, int COEF, int OBF16>
__global__ __launch_bounds__(256) void gemm_tile(
    const float* __restrict__ A, const float* __restrict__ B,
    const float* __restrict__ bias, void* __restrict__ C,
    const float* __restrict__ av, float* __restrict__ fsrc,
    float* __restrict__ fdst,
    size_t asG, size_t bsH, size_t bsG, size_t csH, size_t csG) {
  constexpr int TX = NDIM / 4;
  constexpr int TY = 256 / TX;
  constexpr int BR = TY * RPTY;
  __shared__ float sA[32 * (BR + 4)];
  __shared__ float sB[32 * (NDIM + 4)];
  const int g = blockIdx.z, h = blockIdx.y;
  const int gh = g * NHEADS + h;
  void* Cp;
  if constexpr (OBF16)
    Cp = (void*)((unsigned short*)C + (size_t)g * csG + (size_t)h * csH);
  else
    Cp = (void*)((float*)C + (size_t)g * csG + (size_t)h * csH);
  gemm_body<KDIM, NDIM, RPTY, ACT, COEF, OBF16>(
      A + (size_t)g * asG, B + (size_t)g * bsG + (size_t)h * bsH, bias, Cp,
      COEF ? av + (size_t)gh * 2 * NDIM : nullptr,
      COEF ? fsrc + (size_t)gh * NN : nullptr,
      COEF ? fdst + (size_t)gh * NN : nullptr,
      (int)blockIdx.x * BR, sA, sB);
}

// ---------------------------------------------------------------------------
// Sparse masked softmax + aggregation + ELU, one (n,h,g) per wave.
// Gather reads bf16 Wh: each lane loads uint4 = 8 bf16 channels (16B);
// CPL = O/8 lanes per edge row, EPW = 64/CPL edges in parallel, x2 unroll.
#define GATB(ACC, JJ)                                                          \
  {                                                                            \
    const float w_ = wgt[wave][JJ];                                            \
    const uint4 v_ = *(const uint4*)(WhH + (size_t)midx[wave][JJ] * O + c8);   \
    ACC[0] += w_ * __uint_as_float(v_.x << 16);                                \
    ACC[1] += w_ * __uint_as_float(v_.x & 0xffff0000u);                        \
    ACC[2] += w_ * __uint_as_float(v_.y << 16);                                \
    ACC[3] += w_ * __uint_as_float(v_.y & 0xffff0000u);                        \
    ACC[4] += w_ * __uint_as_float(v_.z << 16);                                \
    ACC[5] += w_ * __uint_as_float(v_.z & 0xffff0000u);                        \
    ACC[6] += w_ * __uint_as_float(v_.w << 16);                                \
    ACC[7] += w_ * __uint_as_float(v_.w & 0xffff0000u);                        \
  }

template <int O>
__global__ __launch_bounds__(256) void aggregate(
    const unsigned short* __restrict__ Wh, const float* __restrict__ fsrc,
    const float* __restrict__ fdst, const int* __restrict__ eidx,
    const int* __restrict__ ecnt, float* __restrict__ Hout) {
  constexpr int CPL = O / 8;     // lanes per edge row
  constexpr int EPW = 64 / CPL;  // edges in parallel
  __shared__ float wgt[4][CAP];
  __shared__ int midx[4][CAP];
  const int wave = threadIdx.x >> 6;
  const int lane = threadIdx.x & 63;
  const int n = blockIdx.x * 4 + wave;
  const int h = blockIdx.y, g = blockIdx.z;
  const int gh = g * NHEADS + h;
  const int cnt = ecnt[(size_t)g * NN + n];
  const int* ei = eidx + (size_t)(g * NN + n) * CAP;
  const float fs = fsrc[(size_t)gh * NN + n];
  const float* fd = fdst + (size_t)gh * NN;
  float mx = -3.4e38f;
  for (int j = lane; j < cnt; j += 64) {
    const int m = ei[j];
    float e = fs + fd[m];
    e = e > 0.f ? e : 0.2f * e;  // leaky relu, alpha = 0.2
    midx[wave][j] = m;
    wgt[wave][j] = e;
    mx = fmaxf(mx, e);
  }
  for (int off = 32; off; off >>= 1) mx = fmaxf(mx, __shfl_xor(mx, off));
  float sm = 0.f;
  for (int j = lane; j < cnt; j += 64) {
    const float w = __expf(wgt[wave][j] - mx);
    wgt[wave][j] = w;
    sm += w;
  }
  for (int off = 32; off; off >>= 1) sm += __shfl_xor(sm, off);
  // gather
  const unsigned short* WhH = Wh + (size_t)gh * NN * O;
  const int sub = lane / CPL;
  const int c8 = (lane % CPL) * 8;
  float A0[8] = {0, 0, 0, 0, 0, 0, 0, 0};
  float A1[8] = {0, 0, 0, 0, 0, 0, 0, 0};
  int j = sub;
  for (; j + EPW < cnt; j += 2 * EPW) {
    GATB(A0, j);
    GATB(A1, j + EPW);
  }
  for (; j < cnt; j += EPW) GATB(A0, j);
#pragma unroll
  for (int q = 0; q < 8; ++q) A0[q] += A1[q];
#pragma unroll
  for (int off = CPL; off < 64; off <<= 1)
#pragma unroll
    for (int q = 0; q < 8; ++q) A0[q] += __shfl_xor(A0[q], off);
  if (lane < CPL) {
    const float inv = 1.f / sm;
    float o[8];
#pragma unroll
    for (int q = 0; q < 8; ++q) {
      o[q] = A0[q] * inv;
      o[q] = o[q] > 0.f ? o[q] : (__expf(o[q]) - 1.f);  // elu
    }
    float* dst = Hout + (size_t)g * NN * (NHEADS * O) + (size_t)n * (NHEADS * O) +
                 h * O + lane * 8;
    float4 o0, o1;
    o0.x = o[0]; o0.y = o[1]; o0.z = o[2]; o0.w = o[3];
    o1.x = o[4]; o1.y = o[5]; o1.z = o[6]; o1.w = o[7];
    *(float4*)dst = o0;
    *(float4*)(dst + 4) = o1;
  }
}

// ---------------------------------------------------------------------------
// Fused tail: o2_g = elu(h2_g @ Wi2 + bi2), logits = concat @ Wf + bf,
// log_softmax, l1 = mean|Wf|.
__global__ __launch_bounds__(256) void tail_fused(const float* __restrict__ h2,
                                                  const float* __restrict__ Wi2,
                                                  const float* __restrict__ bi2,
                                                  const float* __restrict__ Wf,
                                                  const float* __restrict__ bfv,
                                                  float* __restrict__ out) {
  constexpr int K = NHEADS * NHID2;  // 128
  __shared__ float A0[16][K + 4];
  __shared__ float A1[16][K + 4];
  __shared__ float Bs[K][NCLASS];
  __shared__ float WfS[2 * NCLASS][NCLASS];
  __shared__ float cat[16][2 * NCLASS + 1];
  const int tid = threadIdx.x;
  const int row0 = blockIdx.x * 16;
  for (int i = tid; i < 16 * (K / 4); i += 256) {
    const int r = i >> 5, e = i & 31;
    *(float4*)&A0[r][e * 4] = *(const float4*)(h2 + (size_t)(row0 + r) * K + e * 4);
    *(float4*)&A1[r][e * 4] =
        *(const float4*)(h2 + (size_t)NN * K + (size_t)(row0 + r) * K + e * 4);
  }
  ((float4*)Bs)[tid] = ((const float4*)Wi2)[tid];
  if (tid < 32) ((float4*)WfS)[tid] = ((const float4*)Wf)[tid];
  __syncthreads();
  const int c = tid & 7;
  const int kk = (tid >> 3) & 1;
  const int r = tid >> 4;
  float s0 = kk ? 0.f : bi2[c], s1 = kk ? 0.f : bi2[c];
#pragma unroll 8
  for (int k = kk * (K / 2); k < (kk + 1) * (K / 2); ++k) {
    s0 += A0[r][k] * Bs[k][c];
    s1 += A1[r][k] * Bs[k][c];
  }
  s0 += __shfl_xor(s0, 8);
  s1 += __shfl_xor(s1, 8);
  if (kk == 0) {
    cat[r][c] = s0 > 0.f ? s0 : (__expf(s0) - 1.f);
    cat[r][NCLASS + c] = s1 > 0.f ? s1 : (__expf(s1) - 1.f);
  }
  __syncthreads();
  float logit = bfv[c];
#pragma unroll
  for (int k = 0; k < 2 * NCLASS; ++k) logit += cat[r][k] * WfS[k][c];
  float m = logit;
#pragma unroll
  for (int off = 4; off; off >>= 1) m = fmaxf(m, __shfl_xor(m, off));
  float s = __expf(logit - m);
#pragma unroll
  for (int off = 4; off; off >>= 1) s += __shfl_xor(s, off);
  if (kk == 0) out[(size_t)(row0 + r) * NCLASS + c] = logit - (logf(s) + m);
  if (blockIdx.x == 0 && tid < 64) {
    float v = fabsf(Wf[tid]) + fabsf(Wf[64 + tid]);
    for (int off = 32; off; off >>= 1) v += __shfl_xor(v, off);
    if (tid == 0) out[NN * NCLASS] = v * (1.f / (2 * NCLASS * NCLASS));
  }
}

// ---------------------------------------------------------------------------
extern "C" void kernel_launch(void* const* d_in, const int* in_sizes, int n_in,
                              void* d_out, int out_size, void* d_ws, size_t ws_size,
                              hipStream_t stream) {
  const float* x = (const float*)d_in[0];
  const float* adj = (const float*)d_in[1];
  const float* W1 = (const float*)d_in[2];
  const float* a1 = (const float*)d_in[3];
  const float* W2 = (const float*)d_in[4];
  const float* a2 = (const float*)d_in[5];
  const float* Wi1 = (const float*)d_in[6];
  const float* bi1 = (const float*)d_in[7];
  const float* Wi2 = (const float*)d_in[8];
  const float* bi2 = (const float*)d_in[9];
  const float* Wf = (const float*)d_in[10];
  const float* bfv = (const float*)d_in[11];
  float* out = (float*)d_out;

  char* ws = (char*)d_ws;
  int* eidx = (int*)ws;            ws += (size_t)NADJ * NN * CAP * 4;             // 4 MB
  int* ecnt = (int*)ws;            ws += (size_t)NADJ * NN * 4;
  unsigned short* Wh1 = (unsigned short*)ws;
  ws += (size_t)NADJ * NHEADS * NN * NHID1 * 2;                                    // 4 MB
  float* fs1 = (float*)ws;         ws += (size_t)NADJ * NHEADS * NN * 4;
  float* fd1 = (float*)ws;         ws += (size_t)NADJ * NHEADS * NN * 4;
  float* h1 = (float*)ws;          ws += (size_t)NADJ * NN * NHEADS * NHID1 * 4;   // 8 MB
  float* x1 = (float*)ws;          ws += (size_t)NADJ * NN * NHID1 * 4;            // 2 MB
  unsigned short* Wh2 = (unsigned short*)ws;
  ws += (size_t)NADJ * NHEADS * NN * NHID2 * 2;                                    // 2 MB
  float* fs2 = (float*)ws;         ws += (size_t)NADJ * NHEADS * NN * 4;
  float* fd2 = (float*)ws;         ws += (size_t)NADJ * NHEADS * NN * 4;
  float* h2 = (float*)ws;          ws += (size_t)NADJ * NN * NHEADS * NHID2 * 4;   // 4 MB

  // K1: L1 GEMM (+coef1, bf16 out) overlapped with edge-list build.
  k1_gemm_edges<<<512 + NADJ * NN / 4, 256, 0, stream>>>(
      x, W1, a1, Wh1, fs1, fd1, adj, eidx, ecnt);

  // L1 aggregate (bf16 gather).
  aggregate<NHID1><<<dim3(NN / 4, NHEADS, NADJ), 256, 0, stream>>>(
      Wh1, fs1, fd1, eidx, ecnt, h1);

  // Interlayer linear + elu (f32).
  gemm_tile<NHEADS * NHID1, NHID1, 2, 1, 0, 0><<<dim3(NN / 32, 1, NADJ), 256, 0, stream>>>(
      h1, Wi1, bi1, x1, nullptr, nullptr, nullptr,
      (size_t)NN * NHEADS * NHID1, 0, 0, 0, (size_t)NN * NHID1);

  // L2 GAT GEMM (+coef2, bf16 out).
  gemm_tile<NHID1, NHID2, 4, 0, 1, 1><<<dim3(NN / 128, NHEADS, NADJ), 256, 0, stream>>>(
      x1, W2, nullptr, Wh2, a2, fs2, fd2,
      (size_t)NN * NHID1, (size_t)NHID1 * NHID2, (size_t)NHEADS * NHID1 * NHID2,
      (size_t)NN * NHID2, (size_t)NHEADS * NN * NHID2);

  // L2 aggregate (bf16 gather).
  aggregate<NHID2><<<dim3(NN / 4, NHEADS, NADJ), 256, 0, stream>>>(
      Wh2, fs2, fd2, eidx, ecnt, h2);

  tail_fused<<<NN / 16, 256, 0, stream>>>(h2, Wi2, bi2, Wf, bfv, out);
}